// Round 8
// baseline (124.705 us; speedup 1.0000x reference)
//
#include <hip/hip_runtime.h>

#define NQ   12
#define DIM  4096
#define NL   4
#define BLK  512

typedef unsigned short u16;
typedef unsigned int   u32;
typedef float f2 __attribute__((ext_vector_type(2)));
typedef float f4v __attribute__((ext_vector_type(4)));

// ---------- compile-time GF(2) linear algebra for the CNOT-chain permutation ----------
struct L12 { u16 b[NQ]; };

static constexpr u32 lap(const L12& A, u32 x){ u32 r=0; for(int p=0;p<NQ;++p) if((x>>p)&1u) r^=A.b[p]; return r; }
static constexpr L12 lcomp(const L12& A, const L12& B){ L12 r{}; for(int p=0;p<NQ;++p) r.b[p]=(u16)lap(A,(u32)B.b[p]); return r; }
static constexpr L12 lident(){ L12 r{}; for(int p=0;p<NQ;++p) r.b[p]=(u16)(1u<<p); return r; }

static constexpr u32 applyT(u32 i){
  i ^= ((i>>0)&1u) << 11;                            // CNOT(11,0): bit11 ^= bit0
  for(int q=10;q>=0;--q){ int pc=11-q, pt=10-q; i ^= ((i>>pc)&1u) << pt; }
  return i;
}
static constexpr L12 lT(){ L12 t{}; for(int p=0;p<NQ;++p) t.b[p]=(u16)applyT(1u<<p); return t; }

static constexpr L12 linv(const L12& A){              // GF(2) Gauss-Jordan
  u16 v[NQ]; u16 u[NQ];
  for(int p=0;p<NQ;++p){ v[p]=A.b[p]; u[p]=(u16)(1u<<p); }
  for(int t=0;t<NQ;++t){
    int p=t; while(!((v[p]>>t)&1u)) ++p;
    u16 tv=v[p]; v[p]=v[t]; v[t]=tv; u16 tu=u[p]; u[p]=u[t]; u[t]=tu;
    for(int k=0;k<NQ;++k) if(k!=t && ((v[k]>>t)&1u)){ v[k]^=v[t]; u[k]^=u[t]; }
  }
  L12 r{}; for(int p=0;p<NQ;++p) r.b[p]=u[p]; return r;
}
static constexpr L12 ltr(const L12& A){
  L12 r{}; for(int p=0;p<NQ;++p) for(int q=0;q<NQ;++q) if((A.b[p]>>q)&1u) r.b[q]=(u16)(r.b[q]|(1u<<p));
  return r;
}
static constexpr int cpop(u32 v){ int n=0; while(v){ n+=(int)(v&1u); v>>=1; } return n; }

struct Tables {
  u16 cm[12][16];   // [step][combo] xor-offsets spanning the 4 gate masks
  u16 wg[12][4];    // [step][gate] parity mask: a0/a1 role selector
  u16 sp[12][4];    // [step] sorted pivot bit positions
  u16 wexp[NQ];     // final <Z> parity masks: rows of (T^4)^{-T}
};

static constexpr Tables make_tables(){
  Tables tb{};
  const L12 T   = lT();
  const L12 Tit = ltr(linv(T));   // T^{-T}
  L12 A = lident();               // A_l = T^l   (stored_index = A_l(true_index))
  L12 W = lident();               // W_l = A_l^{-T}
  for(int l=0;l<NL;++l){
    for(int g=0;g<3;++g){
      const int st = l*3+g;
      u16 mm[4]={0,0,0,0};
      for(int i=0;i<4;++i){ mm[i]=A.b[4*g+i]; tb.wg[st][i]=W.b[4*g+i]; }
      u32 ech[4]={0,0,0,0}; int piv[4]={0,0,0,0};
      for(int i=0;i<4;++i){
        u32 v=mm[i];
        for(int k=0;k<i;++k) if((v>>piv[k])&1u) v^=ech[k];
        int t2=11; while(!((v>>t2)&1u)) --t2;
        piv[i]=t2; ech[i]=v;
      }
      for(int a2=0;a2<4;++a2) for(int b2=a2+1;b2<4;++b2)
        if(piv[b2]<piv[a2]){ int tt=piv[a2]; piv[a2]=piv[b2]; piv[b2]=tt; }
      for(int i=0;i<4;++i) tb.sp[st][i]=(u16)piv[i];
      for(int c=0;c<16;++c){ u32 m=0; for(int i=0;i<4;++i) if((c>>i)&1) m^=mm[i]; tb.cm[st][c]=(u16)m; }
    }
    A = lcomp(A, T);
    W = lcomp(W, Tit);
  }
  for(int p=0;p<NQ;++p) tb.wexp[p]=W.b[p];
  return tb;
}

// ---------- LDS swizzle: slot = j ^ fold(j>>4), fold linear over GF(2) ----------
static constexpr u16 UIMG[12] = {1,2,4,8, 3,5,6,7, 9,10,11,13};

static constexpr u32 swz(u32 j){
  u32 f=0;
  for(int k=4;k<12;++k) if((j>>k)&1u) f ^= (u32)UIMG[k];
  return j ^ (f & 15u);
}

// rank of v[0..n) under bit-mask (≤4 bits)
static constexpr int rankbits(const u16* v, int n, u16 mask){
  u16 bas[4]={0,0,0,0}; int r=0;
  for(int i=0;i<n;++i){
    u16 x=(u16)(v[i]&mask);
    for(int it=0; it<5 && x; ++it){
      int hb=3; while(hb>0 && !((x>>hb)&1u)) --hb;
      if(bas[hb]) x=(u16)(x^bas[hb]); else { bas[hb]=x; ++r; x=0; }
    }
  }
  return r;
}

// E=8 design: per step, register masks = mm[0..2] (8-elem coset in VGPRs),
// lane mask = mm[3] on tid bit 0 (DPP quad_perm xor-1 exchange, pure VALU).
struct Derived {
  u32 lane_c[12][9];  // tid bit k -> (swz(vec)<<4) | (role-parity nibble <<28)
  u32 smb[12][3];     // swz(mm[i])<<4  (rep parity correction, swizzled)
  u32 scmb[12][8];    // swz(combo)<<4  (coset member byte offsets)
  u32 g0lane[9];      // step 0: raw element-index contribution of tid bit k
  u32 u0smb[3];       // step 0: raw mm[i]
  u32 u11lane[9];     // step 11: raw contribution
  u32 u11smb[3];      // step 11: raw mm[i]
  u16 pm[12];         // wexp[11-q]
  u16 mu[12];         // 3-bit Walsh index per output q
};

static constexpr Derived make_derived(){
  const Tables tb = make_tables();
  Derived d{};
  u16 mm11[4]={0,0,0,0};
  for(int st=0; st<12; ++st){
    u16 mm[4];
    for(int i=0;i<4;++i) mm[i]=tb.cm[st][1u<<i];
    if(st==11) for(int i=0;i<4;++i) mm11[i]=mm[i];
    bool isp[12]={false,false,false,false,false,false,false,false,false,false,false,false};
    for(int i=0;i<4;++i) isp[tb.sp[st][i]]=true;
    int np[8]; int nn=0;
    for(int p=0;p<12;++p) if(!isp[p]) np[nn++]=p;
    u16 img[8];
    for(int j=0;j<8;++j) img[j]=(u16)(swz(1u<<np[j])&15u);
    const u16 img0=(u16)(swz((u32)mm[3])&15u);
    // assign tid bits 1..3 for best 16-lane/8-lane phase spread (img0 = tid bit 0)
    int b1=0,b2=1,b3=2,best=-1;
    for(int i1=0;i1<8;++i1)for(int i2=0;i2<8;++i2)for(int i3=0;i3<8;++i3){
      if(i1==i2||i1==i3||i2==i3) continue;
      u16 t8[3]={img0,img[i1],img[i2]};
      u16 t16[4]={img0,img[i1],img[i2],img[i3]};
      const int sc = rankbits(t16,4,15)*10 + rankbits(t8,3,7);
      if(sc>best){ best=sc; b1=i1;b2=i2;b3=i3; }
    }
    int ord[8]={b1,b2,b3,0,0,0,0,0}; int rp=3;
    for(int j=0;j<8;++j){ if(j!=b1&&j!=b2&&j!=b3) ord[rp++]=j; }
    // tid bit 0 = lane mask mm[3]; nib = {0,0,0,1} (duality: <mm3,wg_i>=δ)
    d.lane_c[st][0] = (swz((u32)mm[3])<<4) | (8u<<28);
    if(st==0)  d.g0lane[0]=(u32)mm[3];
    if(st==11) d.u11lane[0]=(u32)mm[3];
    for(int k=1;k<9;++k){
      const int pos=np[ord[k-1]];
      u32 nib=0;
      for(int i=0;i<4;++i) nib|=(u32)((tb.wg[st][i]>>pos)&1u)<<i;
      d.lane_c[st][k]=(swz(1u<<pos)<<4)|(nib<<28);
      if(st==0)  d.g0lane[k]=1u<<pos;
      if(st==11) d.u11lane[k]=1u<<pos;
    }
    for(int i=0;i<3;++i) d.smb[st][i]=swz((u32)mm[i])<<4;
    for(int c=0;c<8;++c){
      u32 m=0;
      for(int i=0;i<3;++i) if((c>>i)&1) m^=(u32)mm[i];
      d.scmb[st][c]=swz(m)<<4;
    }
    if(st==0)  for(int i=0;i<3;++i) d.u0smb[i]=(u32)mm[i];
    if(st==11) for(int i=0;i<3;++i) d.u11smb[i]=(u32)mm[i];
  }
  for(int q=0;q<12;++q){
    d.pm[q]=tb.wexp[11-q];
    u32 m=0;
    for(int i=0;i<3;++i) m|=(u32)(cpop((u32)mm11[i]&(u32)tb.wexp[11-q])&1)<<i;
    d.mu[q]=(u16)m;
  }
  return d;
}

__device__ constexpr Derived DV = make_derived();

// ---------- DPP xor-1 cross-lane exchange (pure VALU, quad_perm [1,0,3,2]) ----------
__device__ __forceinline__ float dppx(float v){
  return __int_as_float(__builtin_amdgcn_mov_dpp(__float_as_int(v), 0xB1, 0xF, 0xF, true));
}
__device__ __forceinline__ f2 dpp2(f2 v){ f2 r; r.x=dppx(v.x); r.y=dppx(v.y); return r; }

// ---------- register gates (3 per step): 3-shear RY + 3-shear RZ, f2 = {row0,row1} ----------
// gwS[g] = {-tan(ty/4), sin(ty/2), tan(tz/2), sin(tz)}   (global phase dropped)
template<int ST, bool WITHW>
__device__ __forceinline__ void reg_gates(f2 (&R)[8], f2 (&I)[8], const float4* __restrict__ gwS){
#pragma unroll
  for(int i=0;i<3;++i){
    const float4 g = gwS[ST*4+i];
    const f2 mt={g.x,g.x}, sy={g.y,g.y}, mtz={-g.z,-g.z}, sz={g.w,g.w};
#pragma unroll
    for(int c=0;c<8;++c){
      if((c>>i)&1) continue;
      const int c1=c|(1<<i);
      f2 uR=__builtin_elementwise_fma(mt,R[c1],R[c]);
      f2 uI=__builtin_elementwise_fma(mt,I[c1],I[c]);
      f2 vR=__builtin_elementwise_fma(sy,uR,R[c1]);
      f2 vI=__builtin_elementwise_fma(sy,uI,I[c1]);
      R[c]=__builtin_elementwise_fma(mt,vR,uR);
      I[c]=__builtin_elementwise_fma(mt,vI,uI);
      if(WITHW){
        f2 t=__builtin_elementwise_fma(mtz,vI,vR);
        vI=__builtin_elementwise_fma(sz,t,vI);
        vR=__builtin_elementwise_fma(mtz,vI,t);
      }
      R[c1]=vR; I[c1]=vI;
    }
  }
}

// ---------- lane gate (4th per step): partner via DPP; role r3 uniform per thread ----------
// gwD[st] = {cos(ty/2), sin(ty/2), tan(tz/2), sin(tz)}
template<int ST, bool WITHW>
__device__ __forceinline__ void lane_gate(f2 (&R)[8], f2 (&I)[8], const float4* __restrict__ gwD, u32 r3m){
  const float4 g = gwD[ST];
  // sigma = r3 ? +sy : -sy   (a0 side: cy*mine - sy*theirs; a1 side: cy*mine + sy*theirs)
  const float sg = __uint_as_float(__float_as_uint(g.y) ^ r3m ^ 0x80000000u);
  const f2 vcy={g.x,g.x}, vsy={sg,sg};
  const float en = r3m ? 1.f : 0.f;        // RZ only on a1 side
  const f2 vmtz={-g.z*en,-g.z*en}, vsz={g.w*en,g.w*en};
#pragma unroll
  for(int c=0;c<8;++c){
    const f2 Rp=dpp2(R[c]), Ip=dpp2(I[c]);
    f2 nR=__builtin_elementwise_fma(vcy,R[c],vsy*Rp);
    f2 nI=__builtin_elementwise_fma(vcy,I[c],vsy*Ip);
    if(WITHW){
      f2 t=__builtin_elementwise_fma(vmtz,nI,nR);
      nI=__builtin_elementwise_fma(vsz,t,nI);
      nR=__builtin_elementwise_fma(vmtz,nI,t);
    }
    R[c]=nR; I[c]=nI;
  }
}

template<int ST, bool WITHW>
__device__ __forceinline__ void mid_step(const u32* msk, char* lds,
                                         const float4* __restrict__ gwS,
                                         const float4* __restrict__ gwD){
  u32 acc=0;
#pragma unroll
  for(int k=0;k<9;++k) acc ^= DV.lane_c[ST][k]&msk[k];
  const u32 nib = acc>>28;
  u32 base = acc & 0x0FFFFFFFu;
#pragma unroll
  for(int i=0;i<3;++i) base ^= DV.smb[ST][i] & (0u-((nib>>i)&1u));
  const u32 r3m = (nib&8u)<<28;
  u32 ad[8]; f2 R[8], I[8];
#pragma unroll
  for(int c=0;c<8;++c){
    ad[c]=base^DV.scmb[ST][c];
    const f4v v=*(const f4v*)(lds+ad[c]);
    R[c]=v.lo; I[c]=v.hi;
  }
  reg_gates<ST,WITHW>(R,I,gwS);
  lane_gate<ST,WITHW>(R,I,gwD,r3m);
#pragma unroll
  for(int c=0;c<8;++c){ f4v v; v.lo=R[c]; v.hi=I[c]; *(f4v*)(lds+ad[c])=v; }
  __syncthreads();
}

__global__ void prep_kernel(const float* __restrict__ w, float4* __restrict__ gwS,
                            float4* __restrict__ gwD){
  const int t = threadIdx.x;
  if(t < NL*NQ){
    const int l=t/NQ, p=t%NQ, q=(NQ-1)-p;
    const float ty=w[(l*NQ+q)*2+0], tz=w[(l*NQ+q)*2+1];
    gwS[t]=make_float4(-tanf(0.25f*ty), sinf(0.5f*ty), tanf(0.5f*tz), sinf(tz));
    if((p&3)==3) gwD[t>>2]=make_float4(cosf(0.5f*ty), sinf(0.5f*ty), tanf(0.5f*tz), sinf(tz));
  }
}

__global__ __launch_bounds__(BLK, 4) void qsim_kernel(const float* __restrict__ x,
                                                      const float4* __restrict__ gwS,
                                                      const float4* __restrict__ gwD,
                                                      float* __restrict__ out)
{
  __shared__ f4v st4[DIM];             // 65536 B: {re0,re1,im0,im1} per basis state
  char* lds = (char*)st4;
  const int tid = threadIdx.x;
  const int bb  = blockIdx.x;

  u32 msk[9];
#pragma unroll
  for(int k=0;k<9;++k) msk[k]=0u-((u32)(tid>>k)&1u);

  // ---- step 0: register masks {1,2,4} -> coset = 8 consecutive floats per row ----
  u32 rep0=0, acc0=0;
#pragma unroll
  for(int k=0;k<9;++k){ rep0 ^= DV.g0lane[k]&msk[k]; acc0 ^= DV.lane_c[0][k]&msk[k]; }
  const u32 nib0 = acc0>>28;
  u32 base0 = acc0 & 0x0FFFFFFFu;
#pragma unroll
  for(int i=0;i<3;++i){ const u32 mi=0u-((nib0>>i)&1u); base0^=DV.smb[0][i]&mi; rep0^=DV.u0smb[i]&mi; }
  const u32 r3m0 = (nib0&8u)<<28;

  f2 R[8], I[8];
  const float* xr0 = x + (size_t)(2*bb)*DIM + rep0;
  const float* xr1 = xr0 + DIM;
  {
    const float4 a0=*reinterpret_cast<const float4*>(xr0);
    const float4 a1=*reinterpret_cast<const float4*>(xr0+4);
    const float4 b0=*reinterpret_cast<const float4*>(xr1);
    const float4 b1=*reinterpret_cast<const float4*>(xr1+4);
    R[0]=(f2){a0.x,b0.x}; R[1]=(f2){a0.y,b0.y}; R[2]=(f2){a0.z,b0.z}; R[3]=(f2){a0.w,b0.w};
    R[4]=(f2){a1.x,b1.x}; R[5]=(f2){a1.y,b1.y}; R[6]=(f2){a1.z,b1.z}; R[7]=(f2){a1.w,b1.w};
#pragma unroll
    for(int c=0;c<8;++c) I[c]=(f2){0.f,0.f};
  }
  reg_gates<0,true>(R,I,gwS);
  lane_gate<0,true>(R,I,gwD,r3m0);
#pragma unroll
  for(int c=0;c<8;++c){ f4v v; v.lo=R[c]; v.hi=I[c];
    *(f4v*)(lds + (base0 ^ DV.scmb[0][c])) = v; }
  __syncthreads();

  // ---- steps 1..10: LDS round trips ----
  mid_step<1,true >(msk,lds,gwS,gwD);
  mid_step<2,true >(msk,lds,gwS,gwD);
  mid_step<3,true >(msk,lds,gwS,gwD);
  mid_step<4,true >(msk,lds,gwS,gwD);
  mid_step<5,true >(msk,lds,gwS,gwD);
  mid_step<6,true >(msk,lds,gwS,gwD);
  mid_step<7,true >(msk,lds,gwS,gwD);
  mid_step<8,true >(msk,lds,gwS,gwD);
  mid_step<9,false>(msk,lds,gwS,gwD);   // last layer: RZ dropped (|amp|^2 readout)
  mid_step<10,false>(msk,lds,gwS,gwD);

  // ---- step 11 + fused Walsh readout (no write-back) ----
  {
    u32 acc=0, urep=0;
#pragma unroll
    for(int k=0;k<9;++k){ acc ^= DV.lane_c[11][k]&msk[k]; urep ^= DV.u11lane[k]&msk[k]; }
    const u32 nib = acc>>28;
    u32 base = acc & 0x0FFFFFFFu;
#pragma unroll
    for(int i=0;i<3;++i){ const u32 mi=0u-((nib>>i)&1u); base ^= DV.smb[11][i]&mi; urep ^= DV.u11smb[i]&mi; }
    const u32 r3m = (nib&8u)<<28;
#pragma unroll
    for(int c=0;c<8;++c){
      const f4v v = *(const f4v*)(lds + (base ^ DV.scmb[11][c]));
      R[c]=v.lo; I[c]=v.hi;
    }
    reg_gates<11,false>(R,I,gwS);
    lane_gate<11,false>(R,I,gwD,r3m);

    f2 pr[8];
#pragma unroll
    for(int c=0;c<8;++c) pr[c]=__builtin_elementwise_fma(R[c],R[c], I[c]*I[c]);
    // Walsh-Hadamard over the 3 combo bits
#pragma unroll
    for(int b=1;b<8;b<<=1){
#pragma unroll
      for(int c=0;c<8;++c){
        if(c&b) continue;
        const f2 u=pr[c], v=pr[c|b];
        pr[c]=u+v; pr[c|b]=u-v;
      }
    }
    f2 accq[12];
#pragma unroll
    for(int q=0;q<12;++q){
      const u32 sb = ((u32)__popc(urep & (u32)DV.pm[q]) & 1u)<<31;
      const f2 a = pr[DV.mu[q]];
      accq[q]=(f2){__uint_as_float(__float_as_uint(a.x)^sb),
                   __uint_as_float(__float_as_uint(a.y)^sb)};
    }
    f2 nrm2 = pr[0];
#pragma unroll
    for(int o=32;o;o>>=1){
      nrm2.x += __shfl_xor(nrm2.x,o);
      nrm2.y += __shfl_xor(nrm2.y,o);
#pragma unroll
      for(int q=0;q<12;++q){
        accq[q].x += __shfl_xor(accq[q].x,o);
        accq[q].y += __shfl_xor(accq[q].y,o);
      }
    }
    __syncthreads();                      // all waves done reading step 11
    f2* wredp = (f2*)lds;                 // alias reduction buffer into state LDS
    const int wid=tid>>6;
    if((tid&63)==0){
#pragma unroll
      for(int q=0;q<12;++q) wredp[wid*13+q]=accq[q];
      wredp[wid*13+12]=nrm2;
    }
    __syncthreads();
    if(tid<NQ){
      f2 s0=(f2){0.f,0.f}, sn=(f2){0.f,0.f};
#pragma unroll
      for(int wv=0;wv<8;++wv){ s0+=wredp[wv*13+tid]; sn+=wredp[wv*13+12]; }
      out[(size_t)(2*bb+0)*NQ+tid]=s0.x/sn.x;
      out[(size_t)(2*bb+1)*NQ+tid]=s0.y/sn.y;
    }
  }
}

extern "C" void kernel_launch(void* const* d_in, const int* in_sizes, int n_in,
                              void* d_out, int out_size, void* d_ws, size_t ws_size,
                              hipStream_t stream) {
  const float* x = (const float*)d_in[0];
  const float* w = (const float*)d_in[1];
  float* out = (float*)d_out;
  float4* gwS = (float4*)d_ws;
  float4* gwD = gwS + NL*NQ;
  const int B = in_sizes[0] / DIM;
  prep_kernel<<<1, 64, 0, stream>>>(w, gwS, gwD);
  qsim_kernel<<<B/2, BLK, 0, stream>>>(x, gwS, gwD, out);
}

// Round 10
// 109.407 us; speedup vs baseline: 1.1398x; 1.1398x over previous
//
#include <hip/hip_runtime.h>

#define NQ   12
#define DIM  4096
#define NL   4
#define BLK  256

typedef unsigned short u16;
typedef unsigned int   u32;
typedef float f2 __attribute__((ext_vector_type(2)));

// ---------- cheap GF(2) helpers (popcount-based: constexpr-step friendly) ----------
static constexpr int pcnt(u32 v){ return __builtin_popcount(v); }
static constexpr int par(u32 v){ return pcnt(v)&1; }
static constexpr int hb(u16 v){ for(int i=11;i>=0;--i) if((v>>i)&1u) return i; return -1; }

// ---------- compile-time GF(2) linear algebra for the CNOT-chain permutation ----------
struct L12 { u16 b[NQ]; };

static constexpr u32 lap(const L12& A, u32 x){ u32 r=0; for(int p=0;p<NQ;++p) if((x>>p)&1u) r^=A.b[p]; return r; }
static constexpr L12 lcomp(const L12& A, const L12& B){ L12 r{}; for(int p=0;p<NQ;++p) r.b[p]=(u16)lap(A,(u32)B.b[p]); return r; }
static constexpr L12 lident(){ L12 r{}; for(int p=0;p<NQ;++p) r.b[p]=(u16)(1u<<p); return r; }

static constexpr u32 applyT(u32 i){
  i ^= ((i>>0)&1u) << 11;                            // CNOT(11,0): bit11 ^= bit0
  for(int q=10;q>=0;--q){ int pc2=11-q, pt=10-q; i ^= ((i>>pc2)&1u) << pt; }
  return i;
}
static constexpr L12 lT(){ L12 t{}; for(int p=0;p<NQ;++p) t.b[p]=(u16)applyT(1u<<p); return t; }

static constexpr L12 linv(const L12& A){              // GF(2) Gauss-Jordan
  u16 v[NQ]={}; u16 u[NQ]={};
  for(int p=0;p<NQ;++p){ v[p]=A.b[p]; u[p]=(u16)(1u<<p); }
  for(int t=0;t<NQ;++t){
    int p=t; while(!((v[p]>>t)&1u)) ++p;
    u16 tv=v[p]; v[p]=v[t]; v[t]=tv; u16 tu=u[p]; u[p]=u[t]; u[t]=tu;
    for(int k=0;k<NQ;++k) if(k!=t && ((v[k]>>t)&1u)){ v[k]^=v[t]; u[k]^=u[t]; }
  }
  L12 r{}; for(int p=0;p<NQ;++p) r.b[p]=u[p]; return r;
}
static constexpr L12 ltr(const L12& A){
  L12 r{}; for(int p=0;p<NQ;++p) for(int q=0;q<NQ;++q) if((A.b[p]>>q)&1u) r.b[q]=(u16)(r.b[q]|(1u<<p));
  return r;
}

struct Tables {
  u16 cm[12][16];   // [step][combo] xor-offsets spanning the 4 gate masks
  u16 wg[12][4];    // [step][gate] parity mask: a0/a1 role selector
  u16 sp[12][4];    // [step] sorted pivot bit positions
  u16 wexp[NQ];     // final <Z> parity masks: rows of (T^4)^{-T}
};

static constexpr Tables make_tables(){
  Tables tb{};
  const L12 T   = lT();
  const L12 Tit = ltr(linv(T));   // T^{-T}
  L12 A = lident();               // A_l = T^l   (stored_index = A_l(true_index))
  L12 W = lident();               // W_l = A_l^{-T}
  for(int l=0;l<NL;++l){
    for(int g=0;g<3;++g){
      const int st = l*3+g;
      u16 mm[4]={0,0,0,0};
      for(int i=0;i<4;++i){ mm[i]=A.b[4*g+i]; tb.wg[st][i]=W.b[4*g+i]; }
      u32 ech[4]={0,0,0,0}; int piv[4]={0,0,0,0};
      for(int i=0;i<4;++i){
        u32 v=mm[i];
        for(int k=0;k<i;++k) if((v>>piv[k])&1u) v^=ech[k];
        int t2=11; while(!((v>>t2)&1u)) --t2;
        piv[i]=t2; ech[i]=v;
      }
      for(int a2=0;a2<4;++a2) for(int b2=a2+1;b2<4;++b2)
        if(piv[b2]<piv[a2]){ int tt=piv[a2]; piv[a2]=piv[b2]; piv[b2]=tt; }
      for(int i=0;i<4;++i) tb.sp[st][i]=(u16)piv[i];
      for(int c=0;c<16;++c){ u32 m=0; for(int i=0;i<4;++i) if((c>>i)&1) m^=mm[i]; tb.cm[st][c]=(u16)m; }
    }
    A = lcomp(A, T);
    W = lcomp(W, Tit);
  }
  for(int p=0;p<NQ;++p) tb.wexp[p]=W.b[p];
  return tb;
}

// ---------- LDS swizzle: slot = j ^ fold(j>>4), fold linear over GF(2) ----------
static constexpr u16 UIMG[12] = {1,2,4,8, 3,5,6,7, 9,10,11,13};

static constexpr u32 swz(u32 j){
  u32 f=0;
  for(int k=4;k<12;++k) if((j>>k)&1u) f ^= (u32)UIMG[k];
  return j ^ (f & 15u);
}

// ---------- echelon / nullspace ----------
struct Ech { u16 s[12]; };
static constexpr u16 ered(const Ech& e, u16 x){
  while(x){
    const int lb=hb(x);
    if(e.s[lb]) x=(u16)(x^e.s[lb]); else break;
  }
  return x;
}
static constexpr bool eadd(Ech& e, u16 x){
  x=ered(e,x); if(!x) return false;
  e.s[hb(x)]=x; return true;
}

struct NullB { u16 v[12]; int n; };
static constexpr NullB nullspace(const u16* rows, int m){
  u16 rr[12]={}; int pcl[12]={}; int nr=0;
  for(int i=0;i<m;++i){
    u16 x=rows[i];
    for(int j=0;j<nr;++j) if((x>>pcl[j])&1u) x=(u16)(x^rr[j]);
    if(!x) continue;
    const int lb=hb(x);
    for(int j=0;j<nr;++j) if((rr[j]>>lb)&1u) rr[j]=(u16)(rr[j]^x);
    rr[nr]=x; pcl[nr]=lb; ++nr;
  }
  NullB nb{};
  for(int f=0;f<12;++f){
    bool isp=false; for(int j=0;j<nr;++j) if(pcl[j]==f) isp=true;
    if(isp) continue;
    u16 x=(u16)(1u<<f);
    for(int j=0;j<nr;++j) if((rr[j]>>f)&1u) x=(u16)(x|(1u<<pcl[j]));
    nb.v[nb.n++]=x;
  }
  return nb;
}

// ---------- R4 per-step tables (fallback path + step-0/11 specials + readout) ----------
struct Derived {
  u32 lane_c[12][8];
  u32 smb[12][4];
  u32 scmb[12][16];
  u32 g0lane[8];
  u32 u11lane[8];
  u32 u11smb[4];
  u16 pm[12];
  u16 mu[12];
};

static constexpr Derived make_derived(){
  const Tables tb = make_tables();
  Derived d{};
  for(int st=0; st<12; ++st){
    bool isp[12]={};
    for(int i=0;i<4;++i) isp[tb.sp[st][i]]=true;
    int np[8]={}; int nn=0;
    for(int p=0;p<12;++p) if(!isp[p]) np[nn++]=p;
    int best=-1;
    for(int ms=0; ms<256; ++ms){
      if(pcnt((u32)ms)!=6) continue;
      u16 bas[4]={0,0,0,0}; int r=0;
      for(int k=0;k<8;++k){
        if(!((ms>>k)&1)) continue;
        u16 x=(u16)(UIMG[np[k]]&15);
        while(x){
          int hbx=3; while(!((x>>hbx)&1)) --hbx;
          if(bas[hbx]) x=(u16)(x^bas[hbx]);
          else { bas[hbx]=x; ++r; x=0; }
        }
      }
      if(r==4){ best=ms; break; }
    }
    if(best<0) best=0x3F;
    int pos[8]={}; int lo=0, hi=6;
    for(int k=0;k<8;++k){ if((best>>k)&1) pos[lo++]=np[k]; else pos[hi++]=np[k]; }
    for(int k=0;k<8;++k){
      const u32 addr = swz(1u<<pos[k])<<3;
      u32 nib=0;
      for(int i=0;i<4;++i) nib |= (u32)((tb.wg[st][i]>>pos[k])&1u)<<i;
      d.lane_c[st][k] = addr | (nib<<28);
      if(st==0)  d.g0lane[k]  = 1u<<pos[k];
      if(st==11) d.u11lane[k] = 1u<<pos[k];
    }
    for(int i=0;i<4;++i)  d.smb[st][i]  = swz((u32)tb.cm[st][1<<i])<<3;
    for(int c=0;c<16;++c) d.scmb[st][c] = swz((u32)tb.cm[st][c])<<3;
    if(st==11) for(int i=0;i<4;++i) d.u11smb[i] = (u32)tb.cm[11][1<<i];
  }
  for(int q=0;q<12;++q){
    d.pm[q] = tb.wexp[11-q];
    u32 m=0;
    for(int i=0;i<4;++i) m |= (u32)(par((u32)tb.cm[11][1u<<i] & (u32)tb.wexp[11-q]))<<i;
    d.mu[q]=(u16)m;
  }
  return d;
}

__device__ constexpr Derived DV = make_derived();

// ---------- shared-lattice pair tables: steps (a, a+1), a even ----------
struct Pair2 {
  u32 lane_c[8];   // tid bit k -> swz(v)<<3 | nibB<<24 | nibA<<28
  u32 smbA[4], smbB[4];   // swz(cm[1<<i])<<3 for steps a / a+1
  u32 sA[16], sB[16];     // swz(cm[c])<<3
  u32 rawlane[8], rawA[4], rawB[4];
  bool ok;
};

static constexpr bool cand_ok(u16 x, bool lowc, const Ech& eA, const Ech& eB,
                              const Ech& bank, bool needbank){
  if(!x) return false;
  if(lowc && (x&15u)) return false;
  if(!ered(eA,x)) return false;
  if(!ered(eB,x)) return false;
  if(needbank){ const u16 img=(u16)(swz(x)&15u); if(!img) return false; if(!ered(bank,img)) return false; }
  return true;
}

static constexpr Pair2 make_pair2(int a, int att){
  Pair2 r{};
  const Tables tb = make_tables();
  const int b=a+1;
  u16 A[4]={}, B[4]={}, rows[8]={};
  for(int i=0;i<4;++i){ A[i]=tb.cm[a][1u<<i]; B[i]=tb.cm[b][1u<<i]; rows[i]=A[i]; rows[4+i]=B[i]; }
  const NullB ann = nullspace(rows,8);
  if(ann.n<2) return r;
  const u16 f6=ann.v[0], f7=ann.v[1];
  const bool lowc = (a==0);    // step-0 reps must be 16-aligned for float4 global loads
  // wave vectors u6,u7: dual pair to (f6,f7)
  u16 u6=0,u7=0;
  for(u32 j=1;j<4096u && !(u6&&u7);++j){
    const u16 x = lowc ? (u16)((j&255u)<<4) : (u16)j;
    if(lowc && j>255u) break;
    if(!x) continue;
    const int s6=par((u32)(x&f6)), s7=par((u32)(x&f7));
    if(!u6 && s6==1 && s7==0) u6=x;
    else if(!u7 && s6==0 && s7==1) u7=x;
  }
  if(!u6||!u7) return r;
  u16 fr[2]={f6,f7};
  const NullB K = nullspace(fr,2);    // 10-dim: ker f6 ∩ ker f7 (contains both spans)
  // 6 lane vectors in K, complementary to span(A) and span(B);
  // first 4 with swz bank-pair images building rank 4 (b64 conflict floor)
  u16 W[6]={};
  Ech eA{}; for(int i=0;i<4;++i) eadd(eA,A[i]);
  Ech eB{}; for(int i=0;i<4;++i) eadd(eB,B[i]);
  Ech bank{};
  for(int k=0;k<6;++k){
    u16 pick=0;
    for(int pref=1; pref>=0 && !pick; --pref){
      const bool nb = (k<4) && (pref==1);
      int skip = att;
      for(int i1=0;i1<K.n && !pick;++i1){
        const u16 x=K.v[i1];
        if(cand_ok(x,lowc,eA,eB,bank,nb)){ if(skip){--skip;} else pick=x; }
      }
      for(int i1=0;i1<K.n && !pick;++i1)
        for(int j1=i1+1;j1<K.n && !pick;++j1){
          const u16 x=(u16)(K.v[i1]^K.v[j1]);
          if(cand_ok(x,lowc,eA,eB,bank,nb)){ if(skip){--skip;} else pick=x; }
        }
      for(int i1=0;i1<4 && !pick;++i1)
        for(int j1=i1+1;j1<K.n && !pick;++j1)
          for(int l1=j1+1;l1<K.n && !pick;++l1){
            const u16 x=(u16)(K.v[i1]^K.v[j1]^K.v[l1]);
            if(cand_ok(x,lowc,eA,eB,bank,nb)){ if(skip){--skip;} else pick=x; }
          }
    }
    if(!pick) return r;
    W[k]=pick; eadd(eA,pick); eadd(eB,pick);
    if(k<4){ const u16 img=(u16)(swz(pick)&15u); if(img) eadd(bank,img); }
  }
  const u16 vv[8] = {W[0],W[1],W[2],W[3],W[4],W[5],u6,u7};
  // beta[j]_i = <mmA_j, wgB_i>  (role shift of A-correction seen by step b)
  u16 beta[4]={};
  for(int j=0;j<4;++j){
    u16 m=0;
    for(int i=0;i<4;++i) m|=(u16)(par((u32)(A[j]&tb.wg[b][i]))<<i);
    beta[j]=m;
  }
  for(int k=0;k<8;++k){
    const u16 v=vv[k];
    u32 nibA=0, nibB=0;
    for(int i=0;i<4;++i) nibA|=(u32)par((u32)(v&tb.wg[a][i]))<<i;
    for(int i=0;i<4;++i) nibB|=(u32)par((u32)(v&tb.wg[b][i]))<<i;
    for(int j=0;j<4;++j) if((nibA>>j)&1u) nibB^=(u32)beta[j];
    r.lane_c[k]=(swz((u32)v)<<3)|(nibB<<24)|(nibA<<28);
    r.rawlane[k]=(u32)v;
  }
  for(int i=0;i<4;++i){
    r.smbA[i]=swz((u32)A[i])<<3; r.smbB[i]=swz((u32)B[i])<<3;
    r.rawA[i]=(u32)A[i];         r.rawB[i]=(u32)B[i];
  }
  for(int c=0;c<16;++c){ r.sA[c]=swz((u32)tb.cm[a][c])<<3; r.sB[c]=swz((u32)tb.cm[b][c])<<3; }
  // bijectivity: (t,c) -> repA_t ^ cm[c] must be rank 12 for BOTH steps
  u16 gens[8]={};
  for(int k=0;k<8;++k){
    const u32 nibA=(r.lane_c[k]>>28)&15u;
    u16 g=vv[k];
    for(int j=0;j<4;++j) if((nibA>>j)&1u) g=(u16)(g^A[j]);
    gens[k]=g;
  }
  {
    Ech e{}; int rk=0;
    for(int k=0;k<8;++k) if(eadd(e,gens[k])) ++rk;
    for(int i=0;i<4;++i) if(eadd(e,B[i])) ++rk;
    if(rk!=12) return r;
  }
  {
    Ech e{}; int rk=0;
    for(int k=0;k<8;++k) if(eadd(e,gens[k])) ++rk;
    for(int i=0;i<4;++i) if(eadd(e,A[i])) ++rk;
    if(rk!=12) return r;
  }
  if(lowc){ for(int k=0;k<8;++k) if(vv[k]&15u) return r; }
  r.ok=true;
  return r;
}

static constexpr Pair2 mkpair(int a){
  {
    const Pair2 p = make_pair2(a,0);
    if(p.ok) return p;
  }
  {
    const Pair2 p = make_pair2(a,1);
    if(p.ok) return p;
  }
  Pair2 bad{}; bad.ok=false; return bad;
}

// separate constexpr variables: each gets its own constexpr-step budget
static constexpr Pair2 P0h = mkpair(0);
static constexpr Pair2 P1h = mkpair(2);
static constexpr Pair2 P2h = mkpair(4);
static constexpr Pair2 P3h = mkpair(6);
static constexpr Pair2 P4h = mkpair(8);
static constexpr Pair2 P5h = mkpair(10);

__device__ constexpr Pair2 PAIRS[6] = {P0h,P1h,P2h,P3h,P4h,P5h};

// ---------- gates: 3-shear RY + 3-shear RZ (R4-proven), roles = combo bits ----------
// gw[g] = {tan(ty/4), sin(ty/2), tan(tz/2), sin(tz)}  (global phase dropped)
template<int ST, bool WITHW>
__device__ __forceinline__ void gates(f2 (&a)[16], const float4* __restrict__ gw){
#pragma unroll
  for(int i=0;i<4;++i){
    const float4 g = gw[ST*4+i];
#pragma unroll
    for(int c=0;c<16;++c){
      if((c>>i)&1) continue;
      const int c1 = c|(1<<i);
      f2 u, v;
      u.x = fmaf(-g.x, a[c1].x, a[c].x);  u.y = fmaf(-g.x, a[c1].y, a[c].y);
      v.x = fmaf( g.y, u.x, a[c1].x);     v.y = fmaf( g.y, u.y, a[c1].y);
      a[c].x = fmaf(-g.x, v.x, u.x);      a[c].y = fmaf(-g.x, v.y, u.y);
      if(WITHW){
        const float t = fmaf(-g.z, v.y, v.x);
        v.y = fmaf( g.w, t, v.y);
        v.x = fmaf(-g.z, v.y, t);
      }
      a[c1]=v;
    }
  }
}

// ---------- R4 fallback mid step ----------
template<int ST, bool WITHW>
__device__ __forceinline__ void mid_step(const u32* msk, char* lds, const float4* __restrict__ gw){
  u32 acc=0;
#pragma unroll
  for(int k=0;k<8;++k) acc ^= DV.lane_c[ST][k]&msk[k];
  const u32 nib = acc>>28;
  u32 base = acc & 0x0FFFFFFFu;
#pragma unroll
  for(int i=0;i<4;++i) base ^= DV.smb[ST][i] & (0u-((nib>>i)&1u));
  u32 ad[16]; f2 a[16];
#pragma unroll
  for(int c=0;c<16;++c){
    ad[c] = base ^ DV.scmb[ST][c];
    a[c] = *(const f2*)(lds+ad[c]);
  }
  gates<ST,WITHW>(a,gw);
#pragma unroll
  for(int c=0;c<16;++c){ *(f2*)(lds+ad[c]) = a[c]; }
  __syncthreads();
}

__device__ __forceinline__ void ds_fence(){
  asm volatile("s_waitcnt lgkmcnt(0)" ::: "memory");
}

// ---------- shared-lattice pair (steps SA, SA+1): one barrier instead of two ----------
template<int PI, int SA, bool WA, bool WB>
__device__ __forceinline__ void pair_mid(const u32* msk, char* lds, const float4* __restrict__ gw){
  if constexpr (PAIRS[PI].ok){
    u32 acc=0;
#pragma unroll
    for(int k=0;k<8;++k) acc ^= PAIRS[PI].lane_c[k]&msk[k];
    const u32 nibA=(acc>>28)&15u, nibB=(acc>>24)&15u;
    u32 baseA = acc & 0x00FFFFFFu;
#pragma unroll
    for(int i=0;i<4;++i) baseA ^= PAIRS[PI].smbA[i] & (0u-((nibA>>i)&1u));
    u32 ad[16]; f2 a[16];
#pragma unroll
    for(int c=0;c<16;++c){ ad[c]=baseA ^ PAIRS[PI].sA[c]; a[c]=*(const f2*)(lds+ad[c]); }
    gates<SA,WA>(a,gw);
#pragma unroll
    for(int c=0;c<16;++c){ *(f2*)(lds+ad[c]) = a[c]; }
    ds_fence();                         // wave-local: step-b coset written by this wave only
    u32 baseB = baseA;
#pragma unroll
    for(int i=0;i<4;++i) baseB ^= PAIRS[PI].smbB[i] & (0u-((nibB>>i)&1u));
#pragma unroll
    for(int c=0;c<16;++c){ ad[c]=baseB ^ PAIRS[PI].sB[c]; a[c]=*(const f2*)(lds+ad[c]); }
    gates<SA+1,WB>(a,gw);
#pragma unroll
    for(int c=0;c<16;++c){ *(f2*)(lds+ad[c]) = a[c]; }
    __syncthreads();
  } else {
    mid_step<SA,WA>(msk,lds,gw);
    mid_step<SA+1,WB>(msk,lds,gw);
  }
}

__global__ void prep_kernel(const float* __restrict__ w, float4* __restrict__ gwS){
  const int t = threadIdx.x;
  if(t < NL*NQ){
    const int l=t/NQ, p=t%NQ, q=(NQ-1)-p;
    const float ty=w[(l*NQ+q)*2+0], tz=w[(l*NQ+q)*2+1];
    gwS[t]=make_float4(tanf(0.25f*ty), sinf(0.5f*ty), tanf(0.5f*tz), sinf(tz));
  }
}

__global__ __launch_bounds__(BLK, 4) void qsim_kernel(const float* __restrict__ x,
                                                      const float4* __restrict__ gw,
                                                      float* __restrict__ out)
{
  __shared__ f2 st2[DIM];              // exactly 32768 B
  char* lds = (char*)st2;
  const int tid = threadIdx.x;
  const int bb  = blockIdx.x;

  u32 msk[8];
#pragma unroll
  for(int k=0;k<8;++k) msk[k]=0u-((u32)(tid>>k)&1u);

  // ================= pair (0,1) =================
  if constexpr (PAIRS[0].ok){
    u32 acc=0, rep0=0;
#pragma unroll
    for(int k=0;k<8;++k){ acc ^= PAIRS[0].lane_c[k]&msk[k]; rep0 ^= PAIRS[0].rawlane[k]&msk[k]; }
    const u32 nibA=(acc>>28)&15u, nibB=(acc>>24)&15u;
    u32 baseA = acc & 0x00FFFFFFu;
#pragma unroll
    for(int i=0;i<4;++i){ const u32 mi=0u-((nibA>>i)&1u); baseA ^= PAIRS[0].smbA[i]&mi; rep0 ^= PAIRS[0].rawA[i]&mi; }
    f2 a[16];
    const float* xr = x + (size_t)bb*DIM + rep0;   // rep0 16-aligned (verified at compile time)
#pragma unroll
    for(int s=0;s<4;++s){
      const float4 v = *reinterpret_cast<const float4*>(xr + 4*s);
      a[4*s+0]=(f2){v.x,0.f}; a[4*s+1]=(f2){v.y,0.f};
      a[4*s+2]=(f2){v.z,0.f}; a[4*s+3]=(f2){v.w,0.f};
    }
    gates<0,true>(a,gw);
#pragma unroll
    for(int c=0;c<16;++c){ *(f2*)(lds + (baseA ^ PAIRS[0].sA[c])) = a[c]; }
    ds_fence();
    u32 baseB = baseA;
#pragma unroll
    for(int i=0;i<4;++i) baseB ^= PAIRS[0].smbB[i] & (0u-((nibB>>i)&1u));
    u32 ad[16];
#pragma unroll
    for(int c=0;c<16;++c){ ad[c]=baseB ^ PAIRS[0].sB[c]; a[c]=*(const f2*)(lds+ad[c]); }
    gates<1,true>(a,gw);
#pragma unroll
    for(int c=0;c<16;++c){ *(f2*)(lds+ad[c]) = a[c]; }
    __syncthreads();
  } else {
    // R4 step-0 + step-1 fallback
    u32 rep0=0, acc0=0;
#pragma unroll
    for(int k=0;k<8;++k){ rep0 ^= DV.g0lane[k]&msk[k]; acc0 ^= DV.lane_c[0][k]&msk[k]; }
    const u32 base0 = acc0 & 0x0FFFFFFFu;
    f2 a[16];
    const float* xr = x + (size_t)bb*DIM + rep0;
#pragma unroll
    for(int s=0;s<4;++s){
      const float4 v = *reinterpret_cast<const float4*>(xr + 4*s);
      a[4*s+0]=(f2){v.x,0.f}; a[4*s+1]=(f2){v.y,0.f};
      a[4*s+2]=(f2){v.z,0.f}; a[4*s+3]=(f2){v.w,0.f};
    }
    gates<0,true>(a,gw);
#pragma unroll
    for(int c=0;c<16;++c){ *(f2*)(lds + (base0 ^ DV.scmb[0][c])) = a[c]; }
    __syncthreads();
    mid_step<1,true>(msk,lds,gw);
  }

  // ================= pairs (2,3) .. (8,9) =================
  pair_mid<1,2,true,true >(msk,lds,gw);
  pair_mid<2,4,true,true >(msk,lds,gw);
  pair_mid<3,6,true,true >(msk,lds,gw);
  pair_mid<4,8,true,false>(msk,lds,gw);   // step 9 starts last layer: RZ dropped

  // ================= pair (10,11) + fused Walsh readout =================
  f2 a[16]; u32 urep=0;
  if constexpr (PAIRS[5].ok){
    u32 acc=0;
#pragma unroll
    for(int k=0;k<8;++k){ acc ^= PAIRS[5].lane_c[k]&msk[k]; urep ^= PAIRS[5].rawlane[k]&msk[k]; }
    const u32 nibA=(acc>>28)&15u, nibB=(acc>>24)&15u;
    u32 baseA = acc & 0x00FFFFFFu;
#pragma unroll
    for(int i=0;i<4;++i){ const u32 mi=0u-((nibA>>i)&1u); baseA ^= PAIRS[5].smbA[i]&mi; urep ^= PAIRS[5].rawA[i]&mi; }
    u32 ad[16];
#pragma unroll
    for(int c=0;c<16;++c){ ad[c]=baseA ^ PAIRS[5].sA[c]; a[c]=*(const f2*)(lds+ad[c]); }
    gates<10,false>(a,gw);
#pragma unroll
    for(int c=0;c<16;++c){ *(f2*)(lds+ad[c]) = a[c]; }
    ds_fence();
    u32 baseB = baseA;
#pragma unroll
    for(int i=0;i<4;++i){ const u32 mi=0u-((nibB>>i)&1u); baseB ^= PAIRS[5].smbB[i]&mi; urep ^= PAIRS[5].rawB[i]&mi; }
#pragma unroll
    for(int c=0;c<16;++c){ a[c]=*(const f2*)(lds + (baseB ^ PAIRS[5].sB[c])); }
    gates<11,false>(a,gw);
  } else {
    mid_step<10,false>(msk,lds,gw);
    u32 acc=0;
#pragma unroll
    for(int k=0;k<8;++k){ acc ^= DV.lane_c[11][k]&msk[k]; urep ^= DV.u11lane[k]&msk[k]; }
    const u32 nib = acc>>28;
    u32 base = acc & 0x0FFFFFFFu;
#pragma unroll
    for(int i=0;i<4;++i){ const u32 mi=0u-((nib>>i)&1u); base ^= DV.smb[11][i]&mi; urep ^= DV.u11smb[i]&mi; }
#pragma unroll
    for(int c=0;c<16;++c){ a[c] = *(const f2*)(lds + (base ^ DV.scmb[11][c])); }
    gates<11,false>(a,gw);
  }

  // readout (per-thread Walsh over combo bits + block reduction)
  {
    float pr[16];
#pragma unroll
    for(int c=0;c<16;++c) pr[c]=fmaf(a[c].x,a[c].x, a[c].y*a[c].y);
#pragma unroll
    for(int b=1;b<16;b<<=1){
#pragma unroll
      for(int c=0;c<16;++c){
        if(c&b) continue;
        const float u=pr[c], v=pr[c|b];
        pr[c]=u+v; pr[c|b]=u-v;
      }
    }
    float accq[12];
#pragma unroll
    for(int q=0;q<12;++q){
      const u32 sb = ((u32)__popc(urep & (u32)DV.pm[q]) & 1u)<<31;
      accq[q]=__uint_as_float(__float_as_uint(pr[DV.mu[q]])^sb);
    }
    float nrm2 = pr[0];
#pragma unroll
    for(int o=32;o;o>>=1){
      nrm2 += __shfl_xor(nrm2,o);
#pragma unroll
      for(int q=0;q<12;++q) accq[q]+=__shfl_xor(accq[q],o);
    }
    __syncthreads();                      // all waves done reading step-11 data
    float* wredf = (float*)lds;           // alias reduction buffer into state LDS
    const int wid=tid>>6;
    if((tid&63)==0){
#pragma unroll
      for(int q=0;q<12;++q) wredf[wid*13+q]=accq[q];
      wredf[wid*13+12]=nrm2;
    }
    __syncthreads();
    if(tid<NQ){
      const float s0=wredf[0*13+tid]+wredf[1*13+tid]+wredf[2*13+tid]+wredf[3*13+tid];
      const float sn=wredf[0*13+12]+wredf[1*13+12]+wredf[2*13+12]+wredf[3*13+12];
      out[(size_t)bb*NQ+tid]=s0/sn;
    }
  }
}

extern "C" void kernel_launch(void* const* d_in, const int* in_sizes, int n_in,
                              void* d_out, int out_size, void* d_ws, size_t ws_size,
                              hipStream_t stream) {
  const float* x = (const float*)d_in[0];
  const float* w = (const float*)d_in[1];
  float* out = (float*)d_out;
  float4* gwS = (float4*)d_ws;
  const int B = in_sizes[0] / DIM;
  prep_kernel<<<1, 64, 0, stream>>>(w, gwS);
  qsim_kernel<<<B, BLK, 0, stream>>>(x, gwS, out);
}